// Round 5
// baseline (827.773 us; speedup 1.0000x reference)
//
#include <hip/hip_runtime.h>
#include <hip/hip_bf16.h>
#include <math.h>

#define BATCH 8192
#define IN_DIM 1024
#define H_DIM 2048
#define NHEAD 4
#define HEAD_DIM 512
#define EPS_LN 1e-5f

// 256x256 tile, K-tile 64, 2 LDS buffers (128 KiB), 8 waves (2M x 4N),
// 8-phase quadrant schedule (m201-style port).
#define BM 256
#define BN 256

typedef __bf16 bf16x8 __attribute__((ext_vector_type(8)));
typedef short s16x8 __attribute__((ext_vector_type(8)));
typedef float f32x4 __attribute__((ext_vector_type(4)));

__device__ __forceinline__ float b2f(short s) {
  union { unsigned u; float f; } v;
  v.u = ((unsigned)(unsigned short)s) << 16;
  return v.f;
}
__device__ __forceinline__ short f2b(float f) {
  union { float f; unsigned u; } v;
  v.f = f;
  unsigned r = v.u + 0x7fffu + ((v.u >> 16) & 1u);
  return (short)(r >> 16);
}

__device__ __forceinline__ void async_ld16(const short* g, const short* l) {
  __builtin_amdgcn_global_load_lds(
      (const __attribute__((address_space(1))) void*)g,
      (__attribute__((address_space(3))) void*)l, 16, 0, 0);
}

// fp32 -> bf16 (rne), 8 elements/thread
__global__ __launch_bounds__(256) void cvt_k(const float* __restrict__ s,
                                             short* __restrict__ d, int n) {
  int i = (blockIdx.x * 256 + threadIdx.x) * 8;
  if (i >= n) return;
  f32x4 a = *(const f32x4*)(s + i);
  f32x4 b = *(const f32x4*)(s + i + 4);
  s16x8 o;
#pragma unroll
  for (int j = 0; j < 4; j++) o[j] = f2b(a[j]);
#pragma unroll
  for (int j = 0; j < 4; j++) o[4 + j] = f2b(b[j]);
  *(s16x8*)(d + i) = o;
}

enum { EPI_BIAS = 0, EPI_GELU = 1, EPI_GATE = 2 };

// LDS layout (shorts): A buf0 [0,16384) buf1 [16384,32768);
//                      B buf0 [32768,49152) buf1 [49152,65536).  128 KiB.
#define AOFF(b) ((b) * 16384)
#define BOFF(b) (32768 + (b) * 16384)

// Swizzle (K-tile row = 128 B = 8 chunks of 16 B): stored chunk p of row r
// holds logical chunk p ^ (r&7).  Staging applies the involution on the
// GLOBAL source column (LDS dest linear, rule: both-sides-or-neither).
// Read side: chunk (kk*4+g) ^ (fr&7) -> per consecutive-8-lane group all 8
// chunks distinct -> all 32 banks covered -> conflict-free.

// Phase sync helpers.
#define WAITL(n)                                                   \
  asm volatile("s_waitcnt lgkmcnt(" #n ")" ::: "memory");          \
  __builtin_amdgcn_sched_barrier(0)
#define PHEND                                                      \
  __builtin_amdgcn_sched_barrier(0);                               \
  asm volatile("s_waitcnt vmcnt(2)" ::: "memory");                 \
  __builtin_amdgcn_s_barrier();                                    \
  __builtin_amdgcn_sched_barrier(0)

#define RD_A(dst, buf, mihalf)                                                \
  _Pragma("unroll") for (int mi = 0; mi < 4; mi++) {                          \
    dst[mi][0] =                                                              \
        *(const bf16x8*)(lds + AOFF(buf) + aB + ((mihalf)*4 + mi) * 1024 + c0); \
    dst[mi][1] =                                                              \
        *(const bf16x8*)(lds + AOFF(buf) + aB + ((mihalf)*4 + mi) * 1024 + c1); \
  }
#define RD_B(dst, buf, nihalf)                                                \
  _Pragma("unroll") for (int ni = 0; ni < 2; ni++) {                          \
    dst[ni][0] =                                                              \
        *(const bf16x8*)(lds + BOFF(buf) + bB + ((nihalf)*2 + ni) * 1024 + c0); \
    dst[ni][1] =                                                              \
        *(const bf16x8*)(lds + BOFF(buf) + bB + ((nihalf)*2 + ni) * 1024 + c1); \
  }

#define QMFMA(qm, qn, AS, BS)                                                 \
  __builtin_amdgcn_s_setprio(1);                                              \
  _Pragma("unroll") for (int mi = 0; mi < 4; mi++)                            \
      _Pragma("unroll") for (int ni = 0; ni < 2; ni++)                        \
          _Pragma("unroll") for (int kk = 0; kk < 2; kk++)                    \
              acc[(qm)*4 + mi][(qn)*2 + ni] =                                 \
      __builtin_amdgcn_mfma_f32_16x16x32_bf16(                                \
          AS[mi][kk], BS[ni][kk], acc[(qm)*4 + mi][(qn)*2 + ni], 0, 0, 0);    \
  __builtin_amdgcn_s_setprio(0)

// C[M,N] = A[M,K] * W[N,K]^T + bias.  A,W bf16; bias fp32.
// EPI_BIAS/GELU: C bf16.  EPI_GATE: C fp32, fused sigmoid/LN/blend.
// DUAL: k<H_DIM from A, k>=H_DIM from A2.
//
// 8-phase schedule per 2 K64-tiles (ta=even->buf0, tb=odd->buf1).
// Each phase: [ds_read next quadrant's new frags | stage 1 half-tile (2
// global_load_lds) -> lgkmcnt(counted) -> 16 MFMA -> vmcnt(2) -> barrier].
// Every staged half is read exactly 2 phases later (published by the
// intervening phase's vmcnt(2)+barrier); every LDS buffer is re-staged >=2
// barriers after its block-wide read drain (the lgkmcnt(8) phases).
template <int EPI, bool DUAL>
__global__ __launch_bounds__(512, 2) void gemm_bt(
    const short* __restrict__ A, const short* __restrict__ A2,
    const short* __restrict__ W, const float* __restrict__ bias,
    void* __restrict__ Cv, int K, int lda,
    const short* __restrict__ attg, const float* __restrict__ hprev,
    const float* __restrict__ mu, const float* __restrict__ rstd,
    const float* __restrict__ gamma, const float* __restrict__ beta) {
  extern __shared__ __attribute__((aligned(16))) short lds[];
  const int tid = threadIdx.x;
  const int wv = tid >> 6;
  const int lane = tid & 63;
  const int rowBase = blockIdx.x * BM;
  const int colBase = blockIdx.y * BN;
  const int wm = wv >> 2;  // 0..1
  const int wn = wv & 3;   // 0..3
  const int fr = lane & 15;
  const int g = lane >> 4;  // k-chunk group 0..3
  // fragment-read constants (shorts)
  const int c0 = ((g) ^ (fr & 7)) * 8;      // kk=0 swizzled chunk
  const int c1 = ((4 + g) ^ (fr & 7)) * 8;  // kk=1
  const int aB = (wm * 128 + fr) * 64;
  const int bB = (wn * 64 + fr) * 64;
  // staging constants: each instr covers 8 rows x 128B; halves match the
  // read-sets: A_lo rows = [0,64)u[128,192), A_hi +64; B_lo = wn*64+[0,32),
  // B_hi +32.  Wave wv stages 16 rows per half (2 instrs).
  const int sAr = (wv >> 2) * 128 + (wv & 3) * 16;
  const int sBr = (wv >> 1) * 64 + (wv & 1) * 16;
  const int srow = lane >> 3;
  const int sc = ((lane & 7) ^ srow) * 8;  // swizzled global col (elems)
  const int NT = K / 64;  // 16 / 32 / 64 -- always even

  auto stageA = [&](int tt, int half, int buf) {
    int k0 = tt * 64;
    const short* src = A;
    int ak = k0;
    if (DUAL && k0 >= H_DIM) { src = A2; ak = k0 - H_DIM; }
    const int r0 = sAr + half * 64;
#pragma unroll
    for (int i = 0; i < 2; i++)
      async_ld16(src + (size_t)(rowBase + r0 + i * 8 + srow) * lda + ak + sc,
                 lds + AOFF(buf) + (r0 + i * 8) * 64);
  };
  auto stageB = [&](int tt, int half, int buf) {
    const int k0 = tt * 64;
    const int r0 = sBr + half * 32;
#pragma unroll
    for (int i = 0; i < 2; i++)
      async_ld16(W + (size_t)(colBase + r0 + i * 8 + srow) * K + k0 + sc,
                 lds + BOFF(buf) + (r0 + i * 8) * 64);
  };

  f32x4 acc[8][4] = {};
  bf16x8 Al[4][2], Ah[4][2], Bh[2][2], Bl0[2][2], Bl1[2][2];

  // Prologue: stage tile 0 -> buf0; publish A_lo,B_lo,B_hi; pre-read
  // A_lo(0), B_lo(0) (the reads Q11/Q10 of a virtual tile -1 would do).
  stageA(0, 0, 0);
  stageB(0, 0, 0);
  stageB(0, 1, 0);
  stageA(0, 1, 0);
  asm volatile("s_waitcnt vmcnt(2)" ::: "memory");
  __builtin_amdgcn_s_barrier();
  __builtin_amdgcn_sched_barrier(0);
  RD_A(Al, 0, 0);
  RD_B(Bl0, 0, 0);

  for (int t = 0; t < NT; t += 2) {
    // P1 = Q00(ta): frags from buf0
    RD_B(Bh, 0, 1);
    stageA(t + 1, 0, 1);
    WAITL(4);
    QMFMA(0, 0, Al, Bl0);
    PHEND;
    // P2 = Q01(ta)
    RD_A(Ah, 0, 1);
    stageB(t + 1, 0, 1);
    WAITL(8);
    QMFMA(0, 1, Al, Bh);
    PHEND;
    // P3 = Q11(ta): read next tile's A_lo from buf1
    RD_A(Al, 1, 0);
    stageB(t + 1, 1, 1);
    WAITL(8);
    QMFMA(1, 1, Ah, Bh);
    PHEND;
    // P4 = Q10(ta)
    RD_B(Bl1, 1, 0);
    stageA(t + 1, 1, 1);
    WAITL(4);
    QMFMA(1, 0, Ah, Bl0);
    PHEND;
    // P5 = Q00(tb): frags from buf1
    RD_B(Bh, 1, 1);
    if (t + 2 < NT) stageA(t + 2, 0, 0);
    WAITL(4);
    QMFMA(0, 0, Al, Bl1);
    PHEND;
    // P6 = Q01(tb)
    RD_A(Ah, 1, 1);
    if (t + 2 < NT) stageB(t + 2, 0, 0);
    WAITL(8);
    QMFMA(0, 1, Al, Bh);
    PHEND;
    // P7 = Q11(tb)
    RD_A(Al, 0, 0);
    if (t + 2 < NT) stageB(t + 2, 1, 0);
    WAITL(8);
    QMFMA(1, 1, Ah, Bh);
    PHEND;
    // P8 = Q10(tb)
    RD_B(Bl0, 0, 0);
    if (t + 2 < NT) stageA(t + 2, 1, 0);
    WAITL(4);
    QMFMA(1, 0, Ah, Bl1);
    PHEND;
  }

  // C/D layout: col = lane&15, row = (lane>>4)*4 + reg.
  const int ocol0 = colBase + wn * 64 + fr;
  const int orow0 = rowBase + wm * 128 + (g << 2);
#pragma unroll
  for (int mi = 0; mi < 8; mi++) {
#pragma unroll
    for (int ni = 0; ni < 4; ni++) {
      const int col = ocol0 + ni * 16;
      const float bia = bias[col];
#pragma unroll
      for (int r = 0; r < 4; r++) {
        const int row = orow0 + mi * 16 + r;
        float v = acc[mi][ni][r] + bia;
        const size_t idx = (size_t)row * H_DIM + col;
        if (EPI == EPI_BIAS) {
          ((short*)Cv)[idx] = f2b(v);
        } else if (EPI == EPI_GELU) {
          float gg = 0.5f * v * (1.0f + erff(v * 0.70710678118654752f));
          ((short*)Cv)[idx] = f2b(gg);
        } else {
          float gate = 1.0f / (1.0f + expf(-v));
          float hp = hprev[idx];
          float y = hp + b2f(attg[idx]);
          float hc = (y - mu[row]) * rstd[row] * gamma[col] + beta[col];
          ((float*)Cv)[idx] = gate * hc + (1.0f - gate) * hp;
        }
      }
    }
  }
}

// One wave per (b, head). Keys: k1=h, k2=xp, k3=h+xp, k4=h*xp; s3=s1+s2.
// q (bf16) read from `qa`, attn written back over `qa` in place.
__global__ __launch_bounds__(256) void attn_k(short* __restrict__ qa,
                                              const float* __restrict__ h,
                                              const short* __restrict__ xp) {
  const int lane = threadIdx.x & 63;
  const int pair = blockIdx.x * 4 + (threadIdx.x >> 6);  // b*NH + head
  const size_t base =
      (size_t)(pair >> 2) * H_DIM + (size_t)(pair & 3) * HEAD_DIM + lane * 8;
  s16x8 qv = *(const s16x8*)(qa + base);
  f32x4 h0 = *(const f32x4*)(h + base);
  f32x4 h1 = *(const f32x4*)(h + base + 4);
  s16x8 xv = *(const s16x8*)(xp + base);
  float hf[8], xf[8];
  float s1 = 0.f, s2 = 0.f, s4 = 0.f;
#pragma unroll
  for (int j = 0; j < 8; j++) {
    float qf = b2f(qv[j]);
    hf[j] = (j < 4) ? h0[j] : h1[j - 4];
    xf[j] = b2f(xv[j]);
    s1 += qf * hf[j];
    s2 += qf * xf[j];
    s4 += qf * hf[j] * xf[j];
  }
#pragma unroll
  for (int off = 32; off > 0; off >>= 1) {
    s1 += __shfl_xor(s1, off, 64);
    s2 += __shfl_xor(s2, off, 64);
    s4 += __shfl_xor(s4, off, 64);
  }
  const float scale = 0.04419417382415922f;  // 1/sqrt(512)
  float t1 = s1 * scale, t2 = s2 * scale, t3 = (s1 + s2) * scale, t4 = s4 * scale;
  float mx = fmaxf(fmaxf(t1, t2), fmaxf(t3, t4));
  float e1 = expf(t1 - mx), e2 = expf(t2 - mx), e3 = expf(t3 - mx), e4 = expf(t4 - mx);
  float inv = 1.0f / (e1 + e2 + e3 + e4);
  float w1 = e1 * inv, w2 = e2 * inv, w3 = e3 * inv, w4 = e4 * inv;
  float ch = w1 + w3, cx = w2 + w3;
  s16x8 o;
#pragma unroll
  for (int j = 0; j < 8; j++)
    o[j] = f2b(ch * hf[j] + cx * xf[j] + w4 * hf[j] * xf[j]);
  *(s16x8*)(qa + base) = o;
}

// Per-row mean / rstd of (attg(bf16) + h(fp32)).
__global__ __launch_bounds__(256) void rowstats_k(
    const short* __restrict__ attg, const float* __restrict__ h,
    float* __restrict__ mu, float* __restrict__ rstd) {
  __shared__ float sm[8];
  const int row = blockIdx.x;
  const int tid = threadIdx.x;
  const size_t base = (size_t)row * H_DIM + tid * 8;
  s16x8 a = *(const s16x8*)(attg + base);
  f32x4 h0 = *(const f32x4*)(h + base);
  f32x4 h1 = *(const f32x4*)(h + base + 4);
  float s = 0.f, ss = 0.f;
#pragma unroll
  for (int j = 0; j < 8; j++) {
    float y = b2f(a[j]) + ((j < 4) ? h0[j] : h1[j - 4]);
    s += y;
    ss += y * y;
  }
#pragma unroll
  for (int off = 32; off > 0; off >>= 1) {
    s += __shfl_xor(s, off, 64);
    ss += __shfl_xor(ss, off, 64);
  }
  if ((tid & 63) == 0) {
    sm[tid >> 6] = s;
    sm[4 + (tid >> 6)] = ss;
  }
  __syncthreads();
  if (tid == 0) {
    float S = sm[0] + sm[1] + sm[2] + sm[3];
    float SS = sm[4] + sm[5] + sm[6] + sm[7];
    float m = S * (1.0f / H_DIM);
    float var = SS * (1.0f / H_DIM) - m * m;
    mu[row] = m;
    rstd[row] = rsqrtf(fmaxf(var, 0.0f) + EPS_LN);
  }
}

extern "C" void kernel_launch(void* const* d_in, const int* in_sizes, int n_in,
                              void* d_out, int out_size, void* d_ws,
                              size_t ws_size, hipStream_t stream) {
  (void)in_sizes; (void)n_in; (void)out_size; (void)ws_size;
  const float* h_prev = (const float*)d_in[0];
  const float* x      = (const float*)d_in[1];
  const float* W_proj = (const float*)d_in[2];
  const float* b_proj = (const float*)d_in[3];
  const float* W_q    = (const float*)d_in[4];
  const float* b_q    = (const float*)d_in[5];
  const float* W_o    = (const float*)d_in[6];
  const float* b_o    = (const float*)d_in[7];
  const float* W_g    = (const float*)d_in[8];
  const float* b_g    = (const float*)d_in[9];
  const float* gamma  = (const float*)d_in[10];
  const float* beta   = (const float*)d_in[11];
  float* out = (float*)d_out;

  const size_t BH = (size_t)BATCH * H_DIM;       // 16,777,216
  const size_t BI = (size_t)BATCH * IN_DIM;      // 8,388,608
  const size_t NWP = (size_t)H_DIM * IN_DIM;     // 2,097,152
  const size_t NWQ = (size_t)H_DIM * H_DIM;      // 4,194,304
  const size_t NWG = (size_t)H_DIM * 2 * H_DIM;  // 8,388,608

  short* h_bf = (short*)d_ws;
  short* x_bf = h_bf + BH;
  short* wp   = x_bf + BI;
  short* wq   = wp + NWP;
  short* wo   = wq + NWQ;
  short* wg   = wo + NWQ;
  short* bufA = wg + NWG;   // xp, later attn_g
  short* bufB = bufA + BH;  // q, later attn (in place)
  float* mu   = (float*)(bufB + BH);
  float* rstd = mu + BATCH;

  dim3 blk(512);
  dim3 grd(BATCH / BM, H_DIM / BN);  // (32, 8)
  const int SMEM = 65536 * (int)sizeof(short);  // 131072 B
  (void)hipFuncSetAttribute((const void*)gemm_bt<EPI_BIAS, false>,
                            hipFuncAttributeMaxDynamicSharedMemorySize, SMEM);
  (void)hipFuncSetAttribute((const void*)gemm_bt<EPI_GELU, false>,
                            hipFuncAttributeMaxDynamicSharedMemorySize, SMEM);
  (void)hipFuncSetAttribute((const void*)gemm_bt<EPI_GATE, true>,
                            hipFuncAttributeMaxDynamicSharedMemorySize, SMEM);

  dim3 cblk(256);
#define CVT(src, dst, n) \
  cvt_k<<<dim3(((n) / 8 + 255) / 256), cblk, 0, stream>>>(src, dst, (int)(n))

  CVT(h_prev, h_bf, BH);
  CVT(x, x_bf, BI);
  CVT(W_proj, wp, NWP);
  CVT(W_q, wq, NWQ);
  CVT(W_o, wo, NWQ);
  CVT(W_g, wg, NWG);
#undef CVT

  // 1. xp = x @ W_proj^T + b_proj
  gemm_bt<EPI_BIAS, false><<<grd, blk, SMEM, stream>>>(
      x_bf, nullptr, wp, b_proj, bufA, IN_DIM, IN_DIM,
      nullptr, nullptr, nullptr, nullptr, nullptr, nullptr);
  // 2. q = h @ W_q^T + b_q
  gemm_bt<EPI_BIAS, false><<<grd, blk, SMEM, stream>>>(
      h_bf, nullptr, wq, b_q, bufB, H_DIM, H_DIM,
      nullptr, nullptr, nullptr, nullptr, nullptr, nullptr);
  // 3. attention -> bufB (in place over q)
  attn_k<<<dim3(BATCH * NHEAD / 4), cblk, 0, stream>>>(bufB, h_prev, bufA);
  // 4. attn_g = gelu(attn @ W_o^T + b_o) -> bufA
  gemm_bt<EPI_GELU, false><<<grd, blk, SMEM, stream>>>(
      bufB, nullptr, wo, b_o, bufA, H_DIM, H_DIM,
      nullptr, nullptr, nullptr, nullptr, nullptr, nullptr);
  // 5. layernorm stats of (attn_g + h_prev)
  rowstats_k<<<dim3(BATCH), cblk, 0, stream>>>(bufA, h_prev, mu, rstd);
  // 6. gate GEMM (K=4096 over [h, attn_g]) + fused sigmoid/LN/blend -> out
  gemm_bt<EPI_GATE, true><<<grd, blk, SMEM, stream>>>(
      h_bf, bufA, wg, b_g, out, 2 * H_DIM, H_DIM,
      bufA, h_prev, mu, rstd, gamma, beta);
}

// Round 6
// 558.942 us; speedup vs baseline: 1.4810x; 1.4810x over previous
//
#include <hip/hip_runtime.h>
#include <hip/hip_bf16.h>
#include <math.h>

#define BATCH 8192
#define IN_DIM 1024
#define H_DIM 2048
#define NHEAD 4
#define HEAD_DIM 512
#define EPS_LN 1e-5f

// 256x256 tile, K-tile 64, 2 LDS buffers (128 KiB), 8 waves (2M x 4N),
// 8-phase quadrant schedule, read-in-phase/consume-in-phase (m201 pattern).
#define BM 256
#define BN 256

typedef __bf16 bf16x8 __attribute__((ext_vector_type(8)));
typedef short s16x8 __attribute__((ext_vector_type(8)));
typedef float f32x4 __attribute__((ext_vector_type(4)));

__device__ __forceinline__ float b2f(short s) {
  union { unsigned u; float f; } v;
  v.u = ((unsigned)(unsigned short)s) << 16;
  return v.f;
}
__device__ __forceinline__ short f2b(float f) {
  union { float f; unsigned u; } v;
  v.f = f;
  unsigned r = v.u + 0x7fffu + ((v.u >> 16) & 1u);
  return (short)(r >> 16);
}

__device__ __forceinline__ void async_ld16(const short* g, const short* l) {
  __builtin_amdgcn_global_load_lds(
      (const __attribute__((address_space(1))) void*)g,
      (__attribute__((address_space(3))) void*)l, 16, 0, 0);
}

// fp32 -> bf16 (rne), 8 elements/thread
__global__ __launch_bounds__(256) void cvt_k(const float* __restrict__ s,
                                             short* __restrict__ d, int n) {
  int i = (blockIdx.x * 256 + threadIdx.x) * 8;
  if (i >= n) return;
  f32x4 a = *(const f32x4*)(s + i);
  f32x4 b = *(const f32x4*)(s + i + 4);
  s16x8 o;
#pragma unroll
  for (int j = 0; j < 4; j++) o[j] = f2b(a[j]);
#pragma unroll
  for (int j = 0; j < 4; j++) o[4 + j] = f2b(b[j]);
  *(s16x8*)(d + i) = o;
}

enum { EPI_BIAS = 0, EPI_GELU = 1, EPI_GATE = 2 };

// LDS layout (shorts): A buf0 [0,16384) buf1 [16384,32768);
//                      B buf0 [32768,49152) buf1 [49152,65536).  128 KiB.
#define AOFF(b) ((b) * 16384)
#define BOFF(b) (32768 + (b) * 16384)

// Swizzle (K-tile row = 128 B = 8 chunks of 16 B): stored chunk p of row r
// holds logical chunk p ^ (r&7); applied on the GLOBAL source column
// (linear LDS dest).  Round-5-verified: SQ_LDS_BANK_CONFLICT == 0.

#define LG0                                                        \
  asm volatile("s_waitcnt lgkmcnt(0)" ::: "memory");               \
  __builtin_amdgcn_sched_barrier(0)
#define VM4 asm volatile("s_waitcnt vmcnt(4)" ::: "memory")
#define VM2 asm volatile("s_waitcnt vmcnt(2)" ::: "memory")
#define VM0 asm volatile("s_waitcnt vmcnt(0)" ::: "memory")
#define BAR                                                        \
  __builtin_amdgcn_s_barrier();                                    \
  __builtin_amdgcn_sched_barrier(0)

#define RD_AQ(dst, buf, qm)                                                   \
  _Pragma("unroll") for (int mi = 0; mi < 4; mi++) {                          \
    dst[mi][0] =                                                              \
        *(const bf16x8*)(lds + AOFF(buf) + aB + ((qm)*4 + mi) * 1024 + c0);   \
    dst[mi][1] =                                                              \
        *(const bf16x8*)(lds + AOFF(buf) + aB + ((qm)*4 + mi) * 1024 + c1);   \
  }
#define RD_BQ(dst, buf, qn)                                                   \
  _Pragma("unroll") for (int ni = 0; ni < 2; ni++) {                          \
    dst[ni][0] =                                                              \
        *(const bf16x8*)(lds + BOFF(buf) + bB + ((qn)*2 + ni) * 1024 + c0);   \
    dst[ni][1] =                                                              \
        *(const bf16x8*)(lds + BOFF(buf) + bB + ((qn)*2 + ni) * 1024 + c1);   \
  }

#define MFMAQ(qm, qn, AS, BS)                                                 \
  __builtin_amdgcn_s_setprio(1);                                              \
  _Pragma("unroll") for (int mi = 0; mi < 4; mi++)                            \
      _Pragma("unroll") for (int ni = 0; ni < 2; ni++)                        \
          _Pragma("unroll") for (int kk = 0; kk < 2; kk++)                    \
              acc[(qm)*4 + mi][(qn)*2 + ni] =                                 \
      __builtin_amdgcn_mfma_f32_16x16x32_bf16(                                \
          AS[mi][kk], BS[ni][kk], acc[(qm)*4 + mi][(qn)*2 + ni], 0, 0, 0);    \
  __builtin_amdgcn_s_setprio(0);                                              \
  __builtin_amdgcn_sched_barrier(0)

// C[M,N] = A[M,K] * W[N,K]^T + bias.  A,W bf16; bias fp32.
// EPI_BIAS/GELU: C bf16.  EPI_GATE: C fp32, fused sigmoid/LN/blend.
// DUAL: k<H_DIM from A, k>=H_DIM from A2.
//
// Phase = { ds_read this quadrant's frags | stage one half-tile (2
// global_load_lds, 3-4 phase lead) | lgkmcnt(0) | 16 MFMA | counted vmcnt |
// barrier }.  Steady-state load queue audited: vmcnt(4) at P1/P2/P4/P5/P6/P8
// ends guarantees each staged half landed before its reader phase; P3/P7
// need no vmcnt.  Tail pair (no staging): vmcnt(2)/vmcnt(0) at P5/P6.
// Live frags: Aq(32) + Bq(16) + Bq2(16) = 64 VGPR  (acc 128 in AGPR;
// 2 waves/SIMD budget 256 -> no spill, unlike round 5's 112-reg 5-set).
template <int EPI, bool DUAL>
__global__ __launch_bounds__(512, 2) void gemm_bt(
    const short* __restrict__ A, const short* __restrict__ A2,
    const short* __restrict__ W, const float* __restrict__ bias,
    void* __restrict__ Cv, int K, int lda,
    const short* __restrict__ attg, const float* __restrict__ hprev,
    const float* __restrict__ mu, const float* __restrict__ rstd,
    const float* __restrict__ gamma, const float* __restrict__ beta) {
  extern __shared__ __attribute__((aligned(16))) short lds[];
  const int tid = threadIdx.x;
  const int wv = tid >> 6;
  const int lane = tid & 63;
  const int rowBase = blockIdx.x * BM;
  const int colBase = blockIdx.y * BN;
  const int wm = wv >> 2;  // 0..1
  const int wn = wv & 3;   // 0..3
  const int fr = lane & 15;
  const int g = lane >> 4;  // k-chunk group 0..3
  const int c0 = ((g) ^ (fr & 7)) * 8;      // kk=0 swizzled chunk (shorts)
  const int c1 = ((4 + g) ^ (fr & 7)) * 8;  // kk=1
  const int aB = (wm * 128 + fr) * 64;
  const int bB = (wn * 64 + fr) * 64;
  // staging: A_lo rows [0,64)u[128,192) (= wm*128+[0,64)), A_hi +64;
  // B_lo rows wn*64+[0,32) union, B_hi +32.  2 loads per stage call.
  const int sAr = (wv >> 2) * 128 + (wv & 3) * 16;
  const int sBr = (wv >> 1) * 64 + (wv & 1) * 16;
  const int srow = lane >> 3;
  const int sc = ((lane & 7) ^ srow) * 8;  // swizzled global col (elems)
  const int NT = K / 64;  // 16 / 32 / 64 -- always even

  auto stageA = [&](int tt, int half, int buf) {
    int k0 = tt * 64;
    const short* src = A;
    int ak = k0;
    if (DUAL && k0 >= H_DIM) { src = A2; ak = k0 - H_DIM; }
    const int r0 = sAr + half * 64;
#pragma unroll
    for (int i = 0; i < 2; i++)
      async_ld16(src + (size_t)(rowBase + r0 + i * 8 + srow) * lda + ak + sc,
                 lds + AOFF(buf) + (r0 + i * 8) * 64);
  };
  auto stageB = [&](int tt, int half, int buf) {
    const int k0 = tt * 64;
    const int r0 = sBr + half * 32;
#pragma unroll
    for (int i = 0; i < 2; i++)
      async_ld16(W + (size_t)(colBase + r0 + i * 8 + srow) * K + k0 + sc,
                 lds + BOFF(buf) + (r0 + i * 8) * 64);
  };

  f32x4 acc[8][4] = {};
  bf16x8 Aq[4][2], Bq[2][2], Bq2[2][2];

  // Prologue: tile 0 -> buf0.  vmcnt(4): A_lo(0), B_lo(0) landed; B_hi/A_hi
  // (newest 4) may fly -- published by P1/P2's vmcnt(4).
  stageA(0, 0, 0);
  stageB(0, 0, 0);
  stageB(0, 1, 0);
  stageA(0, 1, 0);
  VM4;
  BAR;

  for (int t = 0; t < NT; t += 2) {
    const bool more = (t + 2 < NT);
    // P1 (Q00 of tile t, buf0): needs A_lo(t), B_lo(t)
    RD_AQ(Aq, 0, 0);
    RD_BQ(Bq, 0, 0);
    stageA(t + 1, 0, 1);
    LG0;
    MFMAQ(0, 0, Aq, Bq);
    VM4;  // B_hi(t) landed for P2
    BAR;
    // P2 (Q01): needs B_hi(t)
    RD_BQ(Bq2, 0, 1);
    stageB(t + 1, 0, 1);
    LG0;
    MFMAQ(0, 1, Aq, Bq2);
    VM4;  // A_hi(t) landed for P3
    BAR;
    // P3 (Q11): needs A_hi(t)
    RD_AQ(Aq, 0, 1);
    stageB(t + 1, 1, 1);
    LG0;
    MFMAQ(1, 1, Aq, Bq2);
    BAR;  // P4 re-reads old data; no vmcnt needed
    // P4 (Q10): re-read B_lo(t)
    RD_BQ(Bq, 0, 0);
    stageA(t + 1, 1, 1);
    LG0;
    MFMAQ(1, 0, Aq, Bq);
    VM4;  // A_lo(t+1), B_lo(t+1) landed for P5
    BAR;
    // P5 (Q00 of tile t+1, buf1)
    RD_AQ(Aq, 1, 0);
    RD_BQ(Bq, 1, 0);
    if (more) stageA(t + 2, 0, 0);
    LG0;
    MFMAQ(0, 0, Aq, Bq);
    if (more) { VM4; } else { VM2; }  // B_hi(t+1) landed for P6
    BAR;
    // P6 (Q01)
    RD_BQ(Bq2, 1, 1);
    if (more) stageB(t + 2, 0, 0);
    LG0;
    MFMAQ(0, 1, Aq, Bq2);
    if (more) { VM4; } else { VM0; }  // A_hi(t+1) landed for P7
    BAR;
    // P7 (Q11)
    RD_AQ(Aq, 1, 1);
    if (more) stageB(t + 2, 1, 0);
    LG0;
    MFMAQ(1, 1, Aq, Bq2);
    BAR;
    // P8 (Q10): re-read B_lo(t+1)
    RD_BQ(Bq, 1, 0);
    if (more) stageA(t + 2, 1, 0);
    LG0;
    MFMAQ(1, 0, Aq, Bq);
    if (more) {
      VM4;  // A_lo(t+2), B_lo(t+2) landed for next P1
      BAR;
    }
  }

  // C/D layout: col = lane&15, row = (lane>>4)*4 + reg.
  const int ocol0 = colBase + wn * 64 + fr;
  const int orow0 = rowBase + wm * 128 + (g << 2);
#pragma unroll
  for (int mi = 0; mi < 8; mi++) {
#pragma unroll
    for (int ni = 0; ni < 4; ni++) {
      const int col = ocol0 + ni * 16;
      const float bia = bias[col];
#pragma unroll
      for (int r = 0; r < 4; r++) {
        const int row = orow0 + mi * 16 + r;
        float v = acc[mi][ni][r] + bia;
        const size_t idx = (size_t)row * H_DIM + col;
        if (EPI == EPI_BIAS) {
          ((short*)Cv)[idx] = f2b(v);
        } else if (EPI == EPI_GELU) {
          float gg = 0.5f * v * (1.0f + erff(v * 0.70710678118654752f));
          ((short*)Cv)[idx] = f2b(gg);
        } else {
          float gate = 1.0f / (1.0f + expf(-v));
          float hp = hprev[idx];
          float y = hp + b2f(attg[idx]);
          float hc = (y - mu[row]) * rstd[row] * gamma[col] + beta[col];
          ((float*)Cv)[idx] = gate * hc + (1.0f - gate) * hp;
        }
      }
    }
  }
}

// One wave per (b, head). Keys: k1=h, k2=xp, k3=h+xp, k4=h*xp; s3=s1+s2.
// q (bf16) read from `qa`, attn written back over `qa` in place.
__global__ __launch_bounds__(256) void attn_k(short* __restrict__ qa,
                                              const float* __restrict__ h,
                                              const short* __restrict__ xp) {
  const int lane = threadIdx.x & 63;
  const int pair = blockIdx.x * 4 + (threadIdx.x >> 6);  // b*NH + head
  const size_t base =
      (size_t)(pair >> 2) * H_DIM + (size_t)(pair & 3) * HEAD_DIM + lane * 8;
  s16x8 qv = *(const s16x8*)(qa + base);
  f32x4 h0 = *(const f32x4*)(h + base);
  f32x4 h1 = *(const f32x4*)(h + base + 4);
  s16x8 xv = *(const s16x8*)(xp + base);
  float hf[8], xf[8];
  float s1 = 0.f, s2 = 0.f, s4 = 0.f;
#pragma unroll
  for (int j = 0; j < 8; j++) {
    float qf = b2f(qv[j]);
    hf[j] = (j < 4) ? h0[j] : h1[j - 4];
    xf[j] = b2f(xv[j]);
    s1 += qf * hf[j];
    s2 += qf * xf[j];
    s4 += qf * hf[j] * xf[j];
  }
#pragma unroll
  for (int off = 32; off > 0; off >>= 1) {
    s1 += __shfl_xor(s1, off, 64);
    s2 += __shfl_xor(s2, off, 64);
    s4 += __shfl_xor(s4, off, 64);
  }
  const float scale = 0.04419417382415922f;  // 1/sqrt(512)
  float t1 = s1 * scale, t2 = s2 * scale, t3 = (s1 + s2) * scale, t4 = s4 * scale;
  float mx = fmaxf(fmaxf(t1, t2), fmaxf(t3, t4));
  float e1 = expf(t1 - mx), e2 = expf(t2 - mx), e3 = expf(t3 - mx), e4 = expf(t4 - mx);
  float inv = 1.0f / (e1 + e2 + e3 + e4);
  float w1 = e1 * inv, w2 = e2 * inv, w3 = e3 * inv, w4 = e4 * inv;
  float ch = w1 + w3, cx = w2 + w3;
  s16x8 o;
#pragma unroll
  for (int j = 0; j < 8; j++)
    o[j] = f2b(ch * hf[j] + cx * xf[j] + w4 * hf[j] * xf[j]);
  *(s16x8*)(qa + base) = o;
}

// Per-row mean / rstd of (attg(bf16) + h(fp32)).
__global__ __launch_bounds__(256) void rowstats_k(
    const short* __restrict__ attg, const float* __restrict__ h,
    float* __restrict__ mu, float* __restrict__ rstd) {
  __shared__ float sm[8];
  const int row = blockIdx.x;
  const int tid = threadIdx.x;
  const size_t base = (size_t)row * H_DIM + tid * 8;
  s16x8 a = *(const s16x8*)(attg + base);
  f32x4 h0 = *(const f32x4*)(h + base);
  f32x4 h1 = *(const f32x4*)(h + base + 4);
  float s = 0.f, ss = 0.f;
#pragma unroll
  for (int j = 0; j < 8; j++) {
    float y = b2f(a[j]) + ((j < 4) ? h0[j] : h1[j - 4]);
    s += y;
    ss += y * y;
  }
#pragma unroll
  for (int off = 32; off > 0; off >>= 1) {
    s += __shfl_xor(s, off, 64);
    ss += __shfl_xor(ss, off, 64);
  }
  if ((tid & 63) == 0) {
    sm[tid >> 6] = s;
    sm[4 + (tid >> 6)] = ss;
  }
  __syncthreads();
  if (tid == 0) {
    float S = sm[0] + sm[1] + sm[2] + sm[3];
    float SS = sm[4] + sm[5] + sm[6] + sm[7];
    float m = S * (1.0f / H_DIM);
    float var = SS * (1.0f / H_DIM) - m * m;
    mu[row] = m;
    rstd[row] = rsqrtf(fmaxf(var, 0.0f) + EPS_LN);
  }
}

extern "C" void kernel_launch(void* const* d_in, const int* in_sizes, int n_in,
                              void* d_out, int out_size, void* d_ws,
                              size_t ws_size, hipStream_t stream) {
  (void)in_sizes; (void)n_in; (void)out_size; (void)ws_size;
  const float* h_prev = (const float*)d_in[0];
  const float* x      = (const float*)d_in[1];
  const float* W_proj = (const float*)d_in[2];
  const float* b_proj = (const float*)d_in[3];
  const float* W_q    = (const float*)d_in[4];
  const float* b_q    = (const float*)d_in[5];
  const float* W_o    = (const float*)d_in[6];
  const float* b_o    = (const float*)d_in[7];
  const float* W_g    = (const float*)d_in[8];
  const float* b_g    = (const float*)d_in[9];
  const float* gamma  = (const float*)d_in[10];
  const float* beta   = (const float*)d_in[11];
  float* out = (float*)d_out;

  const size_t BH = (size_t)BATCH * H_DIM;       // 16,777,216
  const size_t BI = (size_t)BATCH * IN_DIM;      // 8,388,608
  const size_t NWP = (size_t)H_DIM * IN_DIM;     // 2,097,152
  const size_t NWQ = (size_t)H_DIM * H_DIM;      // 4,194,304
  const size_t NWG = (size_t)H_DIM * 2 * H_DIM;  // 8,388,608

  short* h_bf = (short*)d_ws;
  short* x_bf = h_bf + BH;
  short* wp   = x_bf + BI;
  short* wq   = wp + NWP;
  short* wo   = wq + NWQ;
  short* wg   = wo + NWQ;
  short* bufA = wg + NWG;   // xp, later attn_g
  short* bufB = bufA + BH;  // q, later attn (in place)
  float* mu   = (float*)(bufB + BH);
  float* rstd = mu + BATCH;

  dim3 blk(512);
  dim3 grd(BATCH / BM, H_DIM / BN);  // (32, 8)
  const int SMEM = 65536 * (int)sizeof(short);  // 131072 B
  (void)hipFuncSetAttribute((const void*)gemm_bt<EPI_BIAS, false>,
                            hipFuncAttributeMaxDynamicSharedMemorySize, SMEM);
  (void)hipFuncSetAttribute((const void*)gemm_bt<EPI_GELU, false>,
                            hipFuncAttributeMaxDynamicSharedMemorySize, SMEM);
  (void)hipFuncSetAttribute((const void*)gemm_bt<EPI_GATE, true>,
                            hipFuncAttributeMaxDynamicSharedMemorySize, SMEM);

  dim3 cblk(256);
#define CVT(src, dst, n) \
  cvt_k<<<dim3(((n) / 8 + 255) / 256), cblk, 0, stream>>>(src, dst, (int)(n))

  CVT(h_prev, h_bf, BH);
  CVT(x, x_bf, BI);
  CVT(W_proj, wp, NWP);
  CVT(W_q, wq, NWQ);
  CVT(W_o, wo, NWQ);
  CVT(W_g, wg, NWG);
#undef CVT

  // 1. xp = x @ W_proj^T + b_proj
  gemm_bt<EPI_BIAS, false><<<grd, blk, SMEM, stream>>>(
      x_bf, nullptr, wp, b_proj, bufA, IN_DIM, IN_DIM,
      nullptr, nullptr, nullptr, nullptr, nullptr, nullptr);
  // 2. q = h @ W_q^T + b_q
  gemm_bt<EPI_BIAS, false><<<grd, blk, SMEM, stream>>>(
      h_bf, nullptr, wq, b_q, bufB, H_DIM, H_DIM,
      nullptr, nullptr, nullptr, nullptr, nullptr, nullptr);
  // 3. attention -> bufB (in place over q)
  attn_k<<<dim3(BATCH * NHEAD / 4), cblk, 0, stream>>>(bufB, h_prev, bufA);
  // 4. attn_g = gelu(attn @ W_o^T + b_o) -> bufA
  gemm_bt<EPI_GELU, false><<<grd, blk, SMEM, stream>>>(
      bufB, nullptr, wo, b_o, bufA, H_DIM, H_DIM,
      nullptr, nullptr, nullptr, nullptr, nullptr, nullptr);
  // 5. layernorm stats of (attn_g + h_prev)
  rowstats_k<<<dim3(BATCH), cblk, 0, stream>>>(bufA, h_prev, mu, rstd);
  // 6. gate GEMM (K=4096 over [h, attn_g]) + fused sigmoid/LN/blend -> out
  gemm_bt<EPI_GATE, true><<<grd, blk, SMEM, stream>>>(
      h_bf, bufA, wg, b_g, out, 2 * H_DIM, H_DIM,
      bufA, h_prev, mu, rstd, gamma, beta);
}